// Round 1
// baseline (204.805 us; speedup 1.0000x reference)
//
#include <hip/hip_runtime.h>
#include <hip/hip_bf16.h>

// Problem constants (NoiseEfficientNet): B=32, Cin=96, Cout=144, H=W=56, 3x3 pad1
#define B_    32
#define CIN   96
#define COUT  144
#define H_    56
#define W_    56
#define HW    3136      // 56*56
#define NPIX  100352    // 32*3136
#define KTOT  864       // 9 taps * 96 ci
#define KC    27        // 864 / 32
#define BK    32
#define BKP   40        // padded LDS row (stride 80B, 16B aligned)
#define MT    128       // workgroup pixel tile (2 waves x 64 pixels)

typedef short  short8  __attribute__((ext_vector_type(8)));
typedef float  floatx4 __attribute__((ext_vector_type(4)));

__device__ __forceinline__ unsigned short f2bf(float f) {
    union { float f; unsigned int u; } v; v.f = f;
    unsigned int u = v.u;
    return (unsigned short)((u + 0x7FFFu + ((u >> 16) & 1u)) >> 16);  // RNE
}

// ---------------------------------------------------------------------------
// Prep 1: x [B][Cin][H][W] fp32  ->  xT [B][H][W][Cin] bf16 (NHWC, k-contiguous)
// Tiled LDS transpose: block = 64 hw x 96 ci.
// ---------------------------------------------------------------------------
__global__ __launch_bounds__(256) void transpose_x(const float* __restrict__ x,
                                                   unsigned short* __restrict__ xT) {
    __shared__ __align__(16) unsigned short tile[64][CIN + 8];  // pad -> stride 104
    int b   = blockIdx.x / 49;
    int hw0 = (blockIdx.x % 49) * 64;
    const float* xb = x + (size_t)b * CIN * HW;
    int t = threadIdx.x;
    // coalesced read: per ci row, 16 float4 segments of 4 hw
    for (int i = t; i < CIN * 16; i += 256) {
        int ci = i >> 4, seg = i & 15;
        float4 v = *(const float4*)(xb + (size_t)ci * HW + hw0 + seg * 4);
        int hwl = seg * 4;
        tile[hwl + 0][ci] = f2bf(v.x);
        tile[hwl + 1][ci] = f2bf(v.y);
        tile[hwl + 2][ci] = f2bf(v.z);
        tile[hwl + 3][ci] = f2bf(v.w);
    }
    __syncthreads();
    // coalesced write: each thread writes 24 ci (48B = 3x uint4) of one hw row
    int row = t >> 2, part = t & 3;
    const uint4* s = (const uint4*)&tile[row][part * 24];
    uint4* d = (uint4*)(xT + ((size_t)b * HW + hw0 + row) * CIN + part * 24);
    d[0] = s[0]; d[1] = s[1]; d[2] = s[2];
}

// ---------------------------------------------------------------------------
// Prep 2: Wm [Cout][Cin][3][3] fp32 -> Wt [Cout][k=tap*96+ci] bf16
// ---------------------------------------------------------------------------
__global__ __launch_bounds__(256) void prep_w(const float* __restrict__ Wm,
                                              unsigned short* __restrict__ Wt) {
    int i = blockIdx.x * 256 + threadIdx.x;
    if (i >= COUT * KTOT) return;
    int co = i / KTOT, k = i - co * KTOT;
    int tap = k / CIN, ci = k - tap * CIN;
    Wt[i] = f2bf(Wm[(size_t)co * (CIN * 9) + ci * 9 + tap]);
}

// ---------------------------------------------------------------------------
// Prep 3: E [B][Cout][3][3] fp32 = bm + bx + sum_f extra[b,co,f]*Mclass[co,f,rc,cc]
// rc/cc boundary classes: 0 => h==0 (kh=0 invalid), 1 => interior, 2 => h==55
// ---------------------------------------------------------------------------
__global__ __launch_bounds__(256) void prep_e(const float* __restrict__ extra,
                                              const float* __restrict__ Wx,
                                              const float* __restrict__ bm,
                                              const float* __restrict__ bx,
                                              float* __restrict__ E) {
    int i = blockIdx.x * 256 + threadIdx.x;
    if (i >= B_ * COUT) return;
    int b = i / COUT, co = i - b * COUT;
    float base = bm[co] + bx[co];
    float m[3][3] = {{0,0,0},{0,0,0},{0,0,0}};
    for (int f = 0; f < 3; ++f) {
        float e = extra[(size_t)b * (COUT * 3) + co * 3 + f];
        const float* w = Wx + ((size_t)co * 3 + f) * 9;
        for (int rc = 0; rc < 3; ++rc) {
            int kh0 = (rc == 0) ? 1 : 0;
            int kh1 = (rc == 2) ? 1 : 2;
            for (int cc = 0; cc < 3; ++cc) {
                int kw0 = (cc == 0) ? 1 : 0;
                int kw1 = (cc == 2) ? 1 : 2;
                float s = 0.f;
                for (int kh = kh0; kh <= kh1; ++kh)
                    for (int kw = kw0; kw <= kw1; ++kw)
                        s += w[kh * 3 + kw];
                m[rc][cc] += e * s;
            }
        }
    }
    float* dst = E + (size_t)i * 9;
    for (int rc = 0; rc < 3; ++rc)
        for (int cc = 0; cc < 3; ++cc)
            dst[rc * 3 + cc] = base + m[rc][cc];
}

// ---------------------------------------------------------------------------
// Main: implicit GEMM. Out[p=(b,h,w)][co] = sum_k patches[p][k] * Wt[co][k]
// patches[p][tap*96+ci] = xT[b][h+dh][w+dw][ci] (0 outside), dh=tap/3-1, dw=tap%3-1.
// Workgroup: 128 threads = 2 waves; tile 128 pixels x 144 cout.
// Wave: 64 pixels (4 m-subtiles of 16) x 144 cout (9 n-subtiles of 16).
// mfma_f32_16x16x32_bf16; A frag: m=lane&15, k=(lane>>4)*8+j;
// B frag: n=lane&15, k=(lane>>4)*8+j; D: col=lane&15, row=(lane>>4)*4+reg.
// ---------------------------------------------------------------------------
__global__ __launch_bounds__(128, 1) void conv_gemm(const unsigned short* __restrict__ xT,
                                                    const unsigned short* __restrict__ Wt,
                                                    const float* __restrict__ E,
                                                    float* __restrict__ out) {
    __shared__ __align__(16) unsigned short As[MT * BKP];    // [pix][k]
    __shared__ __align__(16) unsigned short Bs[COUT * BKP];  // [co][k]

    int tid = threadIdx.x;
    int wv = tid >> 6, lane = tid & 63;
    int pixBase = blockIdx.x * MT;

    floatx4 acc[4][9];
    #pragma unroll
    for (int m = 0; m < 4; ++m)
        #pragma unroll
        for (int n = 0; n < 9; ++n)
            acc[m][n] = (floatx4){0.f, 0.f, 0.f, 0.f};

    // decode this thread's staging pixel once (b,h,w fixed across K-steps)
    int p_st = pixBase + tid;
    int b_st  = p_st / HW;
    int hw_st = p_st - b_st * HW;
    int h_st  = hw_st / W_;
    int w_st  = hw_st - h_st * W_;

    for (int kc = 0; kc < KC; ++kc) {
        int tap = kc / 3;                 // k = tap*96 + ci
        int ci0 = (kc - tap * 3) * BK;
        int dh = tap / 3 - 1, dw = tap - (tap / 3) * 3 - 1;

        // ---- stage As: thread t handles pixel t (32 ci = 64B = 4x uint4)
        {
            int h2 = h_st + dh, w2 = w_st + dw;
            uint4 v0 = {0,0,0,0}, v1 = {0,0,0,0}, v2 = {0,0,0,0}, v3 = {0,0,0,0};
            if ((unsigned)h2 < H_ && (unsigned)w2 < W_) {
                const uint4* src = (const uint4*)(xT + ((size_t)b_st * HW + h2 * W_ + w2) * CIN + ci0);
                v0 = src[0]; v1 = src[1]; v2 = src[2]; v3 = src[3];
            }
            uint4* dst = (uint4*)&As[tid * BKP];
            dst[0] = v0; dst[1] = v1; dst[2] = v2; dst[3] = v3;
        }
        // ---- stage Bs: thread handles co = tid (+128)
        for (int co = tid; co < COUT; co += 128) {
            const uint4* src = (const uint4*)(Wt + (size_t)co * KTOT + kc * BK);
            uint4* dst = (uint4*)&Bs[co * BKP];
            dst[0] = src[0]; dst[1] = src[1]; dst[2] = src[2]; dst[3] = src[3];
        }
        __syncthreads();

        int qk = (lane >> 4) * 8;
        int r16 = lane & 15;
        short8 a[4], bf[9];
        #pragma unroll
        for (int m = 0; m < 4; ++m)
            a[m] = *(const short8*)&As[(wv * 64 + m * 16 + r16) * BKP + qk];
        #pragma unroll
        for (int n = 0; n < 9; ++n)
            bf[n] = *(const short8*)&Bs[(n * 16 + r16) * BKP + qk];
        #pragma unroll
        for (int m = 0; m < 4; ++m)
            #pragma unroll
            for (int n = 0; n < 9; ++n)
                acc[m][n] = __builtin_amdgcn_mfma_f32_16x16x32_bf16(a[m], bf[n], acc[m][n], 0, 0, 0);
        __syncthreads();
    }

    // ---- epilogue: out = acc + E[b][co][rc(h)][cc(w)]
    int q = lane >> 4;
    int col = lane & 15;
    #pragma unroll
    for (int m = 0; m < 4; ++m) {
        int p0 = pixBase + wv * 64 + m * 16 + q * 4;   // 4-aligned; 56%4==0 & 3136%4==0
        int b  = p0 / HW;
        int hw0 = p0 - b * HW;
        int h = hw0 / W_;
        int w0 = hw0 - h * W_;                          // multiple of 4 -> no row wrap
        int rc = (h == 0) ? 0 : ((h == H_ - 1) ? 2 : 1);
        #pragma unroll
        for (int n = 0; n < 9; ++n) {
            int co = n * 16 + col;
            const float* Eb = E + ((size_t)b * COUT + co) * 9 + rc * 3;
            float4 v;
            {
                int cc0 = (w0 == 0) ? 0 : ((w0 == W_ - 1) ? 2 : 1);
                int cc1 = (w0 + 1 == W_ - 1) ? 2 : 1;
                int cc2 = (w0 + 2 == W_ - 1) ? 2 : 1;
                int cc3 = (w0 + 3 == W_ - 1) ? 2 : 1;
                v.x = acc[m][n][0] + Eb[cc0];
                v.y = acc[m][n][1] + Eb[cc1];
                v.z = acc[m][n][2] + Eb[cc2];
                v.w = acc[m][n][3] + Eb[cc3];
            }
            *(float4*)(out + ((size_t)b * COUT + co) * HW + hw0) = v;
        }
    }
}

// ---------------------------------------------------------------------------
extern "C" void kernel_launch(void* const* d_in, const int* in_sizes, int n_in,
                              void* d_out, int out_size, void* d_ws, size_t ws_size,
                              hipStream_t stream) {
    const float* x     = (const float*)d_in[0];
    const float* extra = (const float*)d_in[1];
    const float* Wm    = (const float*)d_in[2];
    const float* bm    = (const float*)d_in[3];
    const float* Wx    = (const float*)d_in[4];
    const float* bx    = (const float*)d_in[5];
    float* out = (float*)d_out;

    // ws layout: xT (19,267,584 B) | Wt (248,832 B) | E (165,888 B) = 19,682,304 B
    const size_t XT_BYTES = (size_t)NPIX * CIN * 2;
    const size_t WT_BYTES = (size_t)COUT * KTOT * 2;
    const size_t E_BYTES  = (size_t)B_ * COUT * 9 * 4;
    if (ws_size < XT_BYTES + WT_BYTES + E_BYTES) return;  // fail loudly (poisoned out)

    unsigned short* xT = (unsigned short*)d_ws;
    unsigned short* Wt = (unsigned short*)((char*)d_ws + XT_BYTES);
    float*          E  = (float*)((char*)d_ws + XT_BYTES + WT_BYTES);

    transpose_x<<<B_ * 49, 256, 0, stream>>>(x, xT);
    prep_w<<<(COUT * KTOT + 255) / 256, 256, 0, stream>>>(Wm, Wt);
    prep_e<<<(B_ * COUT + 255) / 256, 256, 0, stream>>>(extra, Wx, bm, bx, E);
    conv_gemm<<<NPIX / MT, 128, 0, stream>>>(xT, Wt, E, out);
}